// Round 1
// baseline (1334.984 us; speedup 1.0000x reference)
//
#include <hip/hip_runtime.h>
#include <cstddef>

// SelfAttention: B=4, C=256, Cq=32, H=W=64, N=4096
// out = gamma * (V @ softmax(clip(Q K^T / sqrt(32), +-5))^T) + x
//
// Round 1: fp32 SIMT baseline.
//   proj_kernel: q,k,vT projections (1x1 convs) into workspace
//   attn_kernel: fused scores->exp->PV with running denominator
//     (clamp to +-5 makes max-subtraction unnecessary: exp in [e^-5, e^5])

#define BB 4
#define CC 256
#define CQ 32
#define NN 4096
#define TQ 32   // queries per attention block
#define TM 64   // key tile

__global__ __launch_bounds__(512) void proj_kernel(
    const float* __restrict__ x,
    const float* __restrict__ Wq, const float* __restrict__ bq,
    const float* __restrict__ Wk, const float* __restrict__ bk,
    const float* __restrict__ Wv, const float* __restrict__ bv,
    float* __restrict__ qo, float* __restrict__ ko, float* __restrict__ vo)
{
  const int blk = blockIdx.x;          // 0..255 = b*64 + ntile
  const int b  = blk >> 6;
  const int n0 = (blk & 63) << 6;
  const int t  = threadIdx.x;          // 0..511
  const int w  = t >> 6;               // wave 0..7
  const int l  = t & 63;               // lane = spatial j within tile

  __shared__ __align__(16) float xs[CC * 64];   // xs[c][j], 64KB

  // stage x tile: x[b, c, n0+j], coalesced float4 along j
  const float* xb = x + (size_t)b * CC * NN + n0;
  #pragma unroll
  for (int u = 0; u < 8; ++u) {
    int idx = t + 512 * u;             // 0..4095 float4s
    int cc = idx >> 4, j4 = idx & 15;
    float4 tmp = *(const float4*)(xb + (size_t)cc * NN + j4 * 4);
    *(float4*)(xs + cc * 64 + j4 * 4) = tmp;
  }
  __syncthreads();

  const size_t nidx = (size_t)(b * NN + n0 + l);

  // 320 output channels (32 q, 32 k, 256 v); wave w owns [w*40, w*40+40)
  for (int og = 0; og < 5; ++og) {
    const int o0 = __builtin_amdgcn_readfirstlane(w * 40 + og * 8);
    float acc[8];
    const float4* r4[8];
    #pragma unroll
    for (int r = 0; r < 8; ++r) {
      acc[r] = 0.f;
      int o = o0 + r;   // group of 8 never straddles the 32/64 boundaries
      const float* row = (o < 32) ? (Wq + (o << 8))
                       : (o < 64) ? (Wk + ((o - 32) << 8))
                                  : (Wv + ((o - 64) << 8));
      r4[r] = (const float4*)row;      // wave-uniform -> scalar loads
    }
    for (int c4 = 0; c4 < 64; ++c4) {
      float x0 = xs[(c4 * 4 + 0) * 64 + l];
      float x1 = xs[(c4 * 4 + 1) * 64 + l];
      float x2 = xs[(c4 * 4 + 2) * 64 + l];
      float x3 = xs[(c4 * 4 + 3) * 64 + l];
      #pragma unroll
      for (int r = 0; r < 8; ++r) {
        float4 wv = r4[r][c4];
        acc[r] = fmaf(wv.x, x0, acc[r]);
        acc[r] = fmaf(wv.y, x1, acc[r]);
        acc[r] = fmaf(wv.z, x2, acc[r]);
        acc[r] = fmaf(wv.w, x3, acc[r]);
      }
    }
    #pragma unroll
    for (int r = 0; r < 8; ++r) {
      int o = o0 + r;
      float bias = (o < 32) ? bq[o] : (o < 64) ? bk[o - 32] : bv[o - 64];
      float val = acc[r] + bias;
      if (o < 32)       qo[nidx * CQ + o] = val;          // q[b,n,cq]
      else if (o < 64)  ko[nidx * CQ + (o - 32)] = val;   // kT[b,n,cq]
      else              vo[nidx * CC + (o - 64)] = val;   // vT[b,n,c]
    }
  }
}

__global__ __launch_bounds__(256) void attn_kernel(
    const float* __restrict__ q, const float* __restrict__ k,
    const float* __restrict__ vT, const float* __restrict__ x,
    const float* __restrict__ gamma, float* __restrict__ out)
{
  const int blk = blockIdx.x;          // 0..511 = b*128 + qtile
  const int b  = blk >> 7;
  const int n0 = (blk & 127) * TQ;
  const int t  = threadIdx.x;          // 0..255
  const int ch = t;                    // channel owned in PV phase
  const int im = t >> 3;               // score row 0..31
  const int sl = t & 7;                // score sub-lane

  __shared__ __align__(16) float k_sh[TM * 36];  // pad 32->36: conflict-free b128
  __shared__ __align__(16) float P_sh[TQ * 68];  // pad 64->68, float4-aligned
  __shared__ float l_sh[TQ];

  float acc[TQ];
  #pragma unroll
  for (int i = 0; i < TQ; ++i) acc[i] = 0.f;
  float denom = 0.f;

  // q row for my score work, held in registers for the whole kernel
  float4 qreg[8];
  const float4* qrow = (const float4*)(q + (size_t)(b * NN + n0 + im) * CQ);
  #pragma unroll
  for (int u = 0; u < 8; ++u) qreg[u] = qrow[u];

  const float scale = 0.17677669529663687f;  // 1/(sqrt(32)+1e-8)

  for (int m0 = 0; m0 < NN; m0 += TM) {
    // stage K tile (coalesced)
    #pragma unroll
    for (int u = 0; u < 8; ++u) {
      int flat = t + 256 * u;          // 0..2047
      int row = flat >> 5, col = flat & 31;
      k_sh[row * 36 + col] = k[(size_t)(b * NN + m0 + row) * CQ + col];
    }
    __syncthreads();   // k_sh ready; also fences prev-iter P_sh readers

    // scores: thread (im, sl) computes jm = sl + 8*jj
    #pragma unroll
    for (int jj = 0; jj < 8; ++jj) {
      int jm = sl + 8 * jj;
      const float4* krow = (const float4*)(k_sh + jm * 36);
      float s = 0.f;
      #pragma unroll
      for (int u = 0; u < 8; ++u) {
        float4 kk = krow[u];
        s = fmaf(qreg[u].x, kk.x, s);
        s = fmaf(qreg[u].y, kk.y, s);
        s = fmaf(qreg[u].z, kk.z, s);
        s = fmaf(qreg[u].w, kk.w, s);
      }
      s *= scale;
      s = fminf(fmaxf(s, -5.f), 5.f);
      float p = __expf(s);
      P_sh[im * 68 + jm] = p;
      denom += p;
    }
    __syncthreads();   // P_sh ready (and k_sh readers done before next stage)

    // PV: thread owns channel ch; v loads coalesced, P reads are broadcasts
    const float* vb = vT + (size_t)(b * NN + m0) * CC + ch;
    #pragma unroll 2
    for (int mm4 = 0; mm4 < 16; ++mm4) {
      float v0 = vb[(mm4 * 4 + 0) * CC];
      float v1 = vb[(mm4 * 4 + 1) * CC];
      float v2 = vb[(mm4 * 4 + 2) * CC];
      float v3 = vb[(mm4 * 4 + 3) * CC];
      #pragma unroll
      for (int i = 0; i < TQ; ++i) {
        float4 p = *(const float4*)(P_sh + i * 68 + mm4 * 4);
        acc[i] = fmaf(p.x, v0, acc[i]);
        acc[i] = fmaf(p.y, v1, acc[i]);
        acc[i] = fmaf(p.z, v2, acc[i]);
        acc[i] = fmaf(p.w, v3, acc[i]);
      }
    }
    // no sync needed here: next stage writes only k_sh, PV never reads k_sh
  }

  // denominator: reduce the 8 sub-lanes of each score row (same wave)
  denom += __shfl_xor(denom, 1);
  denom += __shfl_xor(denom, 2);
  denom += __shfl_xor(denom, 4);
  if (sl == 0) l_sh[im] = denom;
  __syncthreads();

  const float g = gamma[0];
  const float* xr = x   + ((size_t)b * CC + ch) * NN + n0;
  float*     orow = out + ((size_t)b * CC + ch) * NN + n0;
  #pragma unroll
  for (int i = 0; i < TQ; ++i) {
    orow[i] = fmaf(g, acc[i] / l_sh[i], xr[i]);
  }
}

extern "C" void kernel_launch(void* const* d_in, const int* in_sizes, int n_in,
                              void* d_out, int out_size, void* d_ws, size_t ws_size,
                              hipStream_t stream) {
  const float* x     = (const float*)d_in[0];
  const float* Wq    = (const float*)d_in[1];
  const float* bq    = (const float*)d_in[2];
  const float* Wk    = (const float*)d_in[3];
  const float* bk    = (const float*)d_in[4];
  const float* Wv    = (const float*)d_in[5];
  const float* bv    = (const float*)d_in[6];
  const float* gamma = (const float*)d_in[7];
  float* out = (float*)d_out;

  float* ws = (float*)d_ws;
  float* qb = ws;                                  // B*N*CQ  = 2 MB
  float* kb = ws + (size_t)BB * NN * CQ;           // B*N*CQ  = 2 MB
  float* vb = ws + (size_t)2 * BB * NN * CQ;       // B*N*C   = 16 MB

  proj_kernel<<<BB * (NN / 64), 512, 0, stream>>>(x, Wq, bq, Wk, bk, Wv, bv,
                                                  qb, kb, vb);
  attn_kernel<<<BB * (NN / TQ), 256, 0, stream>>>(qb, kb, vb, x, gamma, out);
}

// Round 2
// 213.896 us; speedup vs baseline: 6.2413x; 6.2413x over previous
//
#include <hip/hip_runtime.h>
#include <cstddef>

// SelfAttention MFMA version. B=4, C=256, Cq=32, N=4096.
// out = gamma * (V @ softmax(clip(Q K^T/sqrt(32), +-5))^T) + x
//
// MFMA 16x16x32 bf16 layouts (HW-verified per guide):
//   A-frag: lane holds A[m=lane&15][k=quad*8+j], j=0..7 (16B contiguous in k)
//   B-frag: lane holds B[k=quad*8+j][n=lane&15]          (16B contiguous in k)
//   C/D   : lane holds D[row=quad*4+r][col=lane&15], r=0..3

#define BB 4
#define CC 256
#define CQ 32
#define NN 4096
#define TQ 64
#define TM 64
#define KSTR 40   // k_sh row stride in bf16 (80B: 16B-aligned b128, 2-way banks)
#define PSTR 72   // P_sh row stride in bf16 (144B: 16B-aligned b128)
#define XSTR 66   // x_sh row stride in bf16 (proj)

typedef __attribute__((ext_vector_type(8))) short short8;
typedef __attribute__((ext_vector_type(4))) float floatx4;
typedef __attribute__((ext_vector_type(4))) unsigned short ushortx4;

__device__ __forceinline__ unsigned short f2bf(float x) {
  union { float f; unsigned u; } v; v.f = x;
  unsigned r = v.u + 0x7FFFu + ((v.u >> 16) & 1u);   // RNE
  return (unsigned short)(r >> 16);
}

// ---------------- prep: W fp32 -> Wall bf16 [320][256] ----------------
__global__ __launch_bounds__(256) void prep_kernel(
    const float* __restrict__ Wq, const float* __restrict__ Wk,
    const float* __restrict__ Wv, unsigned short* __restrict__ Wall)
{
  int e = (blockIdx.x * 256 + threadIdx.x) * 4;   // 80 blocks -> 81920 elems
  int o = e >> 8, c = e & 255;
  const float* src = (o < 32) ? (Wq + o * 256 + c)
                   : (o < 64) ? (Wk + (o - 32) * 256 + c)
                              : (Wv + (o - 64) * 256 + c);
  float4 v = *(const float4*)src;
  ushortx4 pk;
  pk[0] = f2bf(v.x); pk[1] = f2bf(v.y); pk[2] = f2bf(v.z); pk[3] = f2bf(v.w);
  *(ushortx4*)(Wall + e) = pk;
}

// ---------------- proj: q[n][32], k[n][32], v[c][n]  (bf16) ----------------
__global__ __launch_bounds__(256, 1) void proj_kernel(
    const float* __restrict__ x, const unsigned short* __restrict__ Wall,
    const float* __restrict__ bq, const float* __restrict__ bk,
    const float* __restrict__ bv,
    unsigned short* __restrict__ qo, unsigned short* __restrict__ ko,
    unsigned short* __restrict__ vo)
{
  const int b  = blockIdx.x >> 6;
  const int n0 = (blockIdx.x & 63) * 64;
  const int t  = threadIdx.x;
  const int w = t >> 6, lane = t & 63, quad = lane >> 4, l16 = lane & 15;

  __shared__ __align__(16) unsigned short x_sh[CC * XSTR];  // [c][n] bf16
  __shared__ float bias_sh[320];

  for (int o = t; o < 320; o += 256)
    bias_sh[o] = (o < 32) ? bq[o] : (o < 64) ? bk[o - 32] : bv[o - 64];

  // stage x tile [256 c][64 n], fp32 -> bf16
  const float* xb = x + (size_t)(b * CC) * NN + n0;
  #pragma unroll
  for (int u = 0; u < 16; ++u) {
    int idx = t + 256 * u;
    int c = idx >> 4, n4 = (idx & 15) * 4;
    float4 v = *(const float4*)(xb + (size_t)c * NN + n4);
    unsigned p0 = (unsigned)f2bf(v.x) | ((unsigned)f2bf(v.y) << 16);
    unsigned p1 = (unsigned)f2bf(v.z) | ((unsigned)f2bf(v.w) << 16);
    *(unsigned*)(x_sh + c * XSTR + n4)     = p0;   // byte (132c+8n4) % 4 == 0
    *(unsigned*)(x_sh + c * XSTR + n4 + 2) = p1;
  }
  __syncthreads();

  floatx4 acc[5][4];
  #pragma unroll
  for (int ro = 0; ro < 5; ++ro)
    #pragma unroll
    for (int fc = 0; fc < 4; ++fc) acc[ro][fc] = (floatx4){0.f, 0.f, 0.f, 0.f};

  #pragma unroll 1
  for (int ks = 0; ks < 8; ++ks) {
    const int k0 = ks * 32;
    short8 bfr[4];
    #pragma unroll
    for (int fc = 0; fc < 4; ++fc) {
      #pragma unroll
      for (int j = 0; j < 8; ++j)
        bfr[fc][j] = (short)x_sh[(k0 + quad * 8 + j) * XSTR + 16 * fc + l16];
    }
    short8 afr[5];
    #pragma unroll
    for (int ro = 0; ro < 5; ++ro)
      afr[ro] = *(const short8*)(Wall + (size_t)(80 * w + 16 * ro + l16) * CC
                                 + k0 + quad * 8);
    #pragma unroll
    for (int ro = 0; ro < 5; ++ro)
      #pragma unroll
      for (int fc = 0; fc < 4; ++fc)
        acc[ro][fc] = __builtin_amdgcn_mfma_f32_16x16x32_bf16(
            afr[ro], bfr[fc], acc[ro][fc], 0, 0, 0);
  }

  // epilogue: D[row=out-ch quad*4+r][col=n l16]
  #pragma unroll
  for (int ro = 0; ro < 5; ++ro) {
    const int ob = 80 * w + 16 * ro;   // wave-uniform; never straddles q/k/v
    #pragma unroll
    for (int fc = 0; fc < 4; ++fc) {
      const int n = n0 + 16 * fc + l16;
      if (ob < 64) {                         // q or k: [n][32], pack 4 along o
        ushortx4 pk;
        #pragma unroll
        for (int r = 0; r < 4; ++r)
          pk[r] = f2bf(acc[ro][fc][r] + bias_sh[ob + quad * 4 + r]);
        unsigned short* dst = (ob < 32) ? qo : ko;
        const int o0 = (ob < 32) ? ob : ob - 32;
        *(ushortx4*)(dst + (size_t)(b * NN + n) * CQ + o0 + quad * 4) = pk;
      } else {                               // v: [c][n]
        #pragma unroll
        for (int r = 0; r < 4; ++r) {
          const int o = ob - 64 + quad * 4 + r;
          vo[(size_t)(b * CC + o) * NN + n] =
              f2bf(acc[ro][fc][r] + bias_sh[ob + quad * 4 + r]);
        }
      }
    }
  }
}

// ---------------- fused attention ----------------
__global__ __launch_bounds__(512, 2) void attn_kernel(
    const unsigned short* __restrict__ qg, const unsigned short* __restrict__ kg,
    const unsigned short* __restrict__ vg, const float* __restrict__ x,
    const float* __restrict__ gamma, float* __restrict__ out)
{
  const int b  = blockIdx.x >> 6;
  const int n0 = (blockIdx.x & 63) * TQ;
  const int t  = threadIdx.x;
  const int w = t >> 6, lane = t & 63, quad = lane >> 4, l16 = lane & 15;

  __shared__ __align__(16) unsigned short k_sh[TM * KSTR];
  __shared__ __align__(16) unsigned short P_sh[TQ * PSTR];
  __shared__ float l_part[2][TQ];

  const int i0 = 16 * (w & 3);   // score-row subtile of this wave
  const int j0 = 32 * (w >> 2);  // score-col base (2 subtiles: j0, j0+16)
  const int c0 = 32 * w;         // PV: channels [c0, c0+32)

  // Q fragment (A operand), held all kernel
  const short8 qf = *(const short8*)(
      qg + ((size_t)(b * NN + n0 + i0 + l16) * CQ + quad * 8));

  floatx4 acc[2][4];
  #pragma unroll
  for (int fc = 0; fc < 2; ++fc)
    #pragma unroll
    for (int fq = 0; fq < 4; ++fq) acc[fc][fq] = (floatx4){0.f, 0.f, 0.f, 0.f};
  float dsum[4] = {0.f, 0.f, 0.f, 0.f};

  const int srow = t >> 3, scol = (t & 7) * 4;   // K staging: 4 bf16/thread
  const unsigned short* kgb = kg + (size_t)(b * NN) * CQ;
  const unsigned short* vgb = vg + (size_t)(b * CC) * NN;
  const floatx4 zero4 = {0.f, 0.f, 0.f, 0.f};
  const float scale = 0.17677669529663687f;      // 1/sqrt(32)

  #pragma unroll 1
  for (int m0 = 0; m0 < NN; m0 += TM) {
    // stage K tile (coalesced 8B/thread)
    *(ushortx4*)(k_sh + srow * KSTR + scol) =
        *(const ushortx4*)(kgb + (size_t)(m0 + srow) * CQ + scol);
    __syncthreads();   // k_sh ready; also: P_sh readers (prev PV) are done

    // scores: S = Q K^T, 2 subtiles per wave
    #pragma unroll
    for (int f = 0; f < 2; ++f) {
      short8 kf = *(const short8*)(k_sh + (j0 + 16 * f + l16) * KSTR + quad * 8);
      floatx4 s = __builtin_amdgcn_mfma_f32_16x16x32_bf16(qf, kf, zero4, 0, 0, 0);
      #pragma unroll
      for (int r = 0; r < 4; ++r) {
        float e = fminf(fmaxf(s[r] * scale, -5.f), 5.f);
        float p = __expf(e);
        dsum[r] += p;
        P_sh[(i0 + quad * 4 + r) * PSTR + (j0 + 16 * f + l16)] = f2bf(p);
      }
    }
    __syncthreads();   // P_sh ready; k_sh readers done before restage

    // PV: O[c][i] += V[c][m] P[i][m];  A=V (global, rows are 128B lines)
    short8 af[2][2], bfr[2][4];
    #pragma unroll
    for (int ks = 0; ks < 2; ++ks) {
      #pragma unroll
      for (int fc = 0; fc < 2; ++fc)
        af[ks][fc] = *(const short8*)(
            vgb + (size_t)(c0 + 16 * fc + l16) * NN + m0 + 32 * ks + quad * 8);
      #pragma unroll
      for (int fq = 0; fq < 4; ++fq)
        bfr[ks][fq] = *(const short8*)(
            P_sh + (16 * fq + l16) * PSTR + 32 * ks + quad * 8);
    }
    #pragma unroll
    for (int ks = 0; ks < 2; ++ks)
      #pragma unroll
      for (int fc = 0; fc < 2; ++fc)
        #pragma unroll
        for (int fq = 0; fq < 4; ++fq)
          acc[fc][fq] = __builtin_amdgcn_mfma_f32_16x16x32_bf16(
              af[ks][fc], bfr[ks][fq], acc[fc][fq], 0, 0, 0);
  }

  // denominator: reduce over the 16 col-lanes (stays within quad)
  #pragma unroll
  for (int off = 1; off < 16; off <<= 1)
    #pragma unroll
    for (int r = 0; r < 4; ++r) dsum[r] += __shfl_xor(dsum[r], off);
  if (l16 == 0) {
    #pragma unroll
    for (int r = 0; r < 4; ++r)
      l_part[w >> 2][i0 + quad * 4 + r] = dsum[r];
  }
  __syncthreads();

  // epilogue: out = gamma*(acc/l) + x
  const float g = gamma[0];
  #pragma unroll
  for (int fq = 0; fq < 4; ++fq) {
    const int iq = 16 * fq + l16;
    const float gl = g / (l_part[0][iq] + l_part[1][iq]);
    #pragma unroll
    for (int fc = 0; fc < 2; ++fc) {
      #pragma unroll
      for (int r = 0; r < 4; ++r) {
        const size_t a =
            (size_t)(b * CC + c0 + 16 * fc + quad * 4 + r) * NN + n0 + iq;
        out[a] = fmaf(acc[fc][fq][r], gl, x[a]);
      }
    }
  }
}

extern "C" void kernel_launch(void* const* d_in, const int* in_sizes, int n_in,
                              void* d_out, int out_size, void* d_ws, size_t ws_size,
                              hipStream_t stream) {
  const float* x     = (const float*)d_in[0];
  const float* Wq    = (const float*)d_in[1];
  const float* bq    = (const float*)d_in[2];
  const float* Wk    = (const float*)d_in[3];
  const float* bk    = (const float*)d_in[4];
  const float* Wv    = (const float*)d_in[5];
  const float* bv    = (const float*)d_in[6];
  const float* gamma = (const float*)d_in[7];
  float* out = (float*)d_out;

  unsigned short* ws   = (unsigned short*)d_ws;
  unsigned short* Wall = ws;                               // 320*256
  unsigned short* qb   = ws + 320 * 256;                   // B*N*32
  unsigned short* kb   = qb + (size_t)BB * NN * CQ;        // B*N*32
  unsigned short* vb   = kb + (size_t)BB * NN * CQ;        // B*C*N

  prep_kernel<<<80, 256, 0, stream>>>(Wq, Wk, Wv, Wall);
  proj_kernel<<<BB * (NN / 64), 256, 0, stream>>>(x, Wall, bq, bk, bv,
                                                  qb, kb, vb);
  attn_kernel<<<BB * (NN / TQ), 512, 0, stream>>>(qb, kb, vb, x, gamma, out);
}